// Round 4
// baseline (843.430 us; speedup 1.0000x reference)
//
#include <hip/hip_runtime.h>
#include <math.h>

#define BB 2
#define SS 2048
#define HIDD 1024
#define NHH 16
#define HDD 64

using f4 = __attribute__((ext_vector_type(4))) float;

// ----------------------------------------------------------------------
// GEMM: C = A[M,K] @ W[K,N] + bias[N]   (M=4096, N=K=1024)
// OUT_MODE 0: plain row-major C[M,N]
// OUT_MODE 1: scatter to q layout [(b*NH+h)*S + s]*HD + d
// 128x64 tile, BK=16, 256 threads, 8x4 micro-tile, double-buffered LDS
// (single barrier per K-step), register-prefetch of next K-tile.
// 1D grid of 512 blocks, XCD-chunked: XCD k owns 4 consecutive m-panels
// (4 x 512KB A-panels = 2MB resident in its 4MB L2).
template<int OUT_MODE>
__global__ __launch_bounds__(256)
void gemm_kernel(const float* __restrict__ A, const float* __restrict__ W,
                 const float* __restrict__ bias, float* __restrict__ C)
{
    constexpr int M = BB * SS, N = HIDD, K = HIDD;
    constexpr int BM = 128, BN = 64, BK = 16, NK = K / BK;
    constexpr int LDA = 132, LDW = 68;   // +4 pad: 2-way banks, 16B-aligned rows
    __shared__ float As[2][BK][LDA];     // [buf][k][m] (transposed A tile)
    __shared__ float Ws[2][BK][LDW];     // [buf][k][n]

    const int tid = threadIdx.x;
    const int tx = tid & 15, ty = tid >> 4;

    // XCD-aware bijective remap: 512 blocks = 8 XCDs x 64
    const int swz = (blockIdx.x & 7) * 64 + (blockIdx.x >> 3);
    const int n0 = (swz & 15) * BN;      // 16 n-blocks (fast within XCD chunk)
    const int m0 = (swz >> 4) * BM;      // 4 m-panels per XCD chunk

    // staging assignments
    const int a_m = tid >> 2;             // A row 0..63 (and +64)
    const int a_k = (tid & 3) * 4;        // A k chunk {0,4,8,12}
    const int w_k = tid >> 4;             // W k row 0..15
    const int w_n = (tid & 15) * 4;       // W col chunk 0..60

    const float* Abase = A + (size_t)m0 * K;
    const float* Wbase = W + n0;

    f4 pa0, pa1, pw0;

#define G_LOAD(kt) {                                                        \
    const float* Ap = Abase + (size_t)(kt) * BK + a_k;                      \
    pa0 = *(const f4*)(Ap + (size_t)a_m * K);                               \
    pa1 = *(const f4*)(Ap + (size_t)(a_m + 64) * K);                        \
    pw0 = *(const f4*)(Wbase + (size_t)((kt) * BK + w_k) * N + w_n); }

#define LDS_WRITE(buf) {                                                    \
    As[buf][a_k+0][a_m]      = pa0[0]; As[buf][a_k+1][a_m]      = pa0[1];   \
    As[buf][a_k+2][a_m]      = pa0[2]; As[buf][a_k+3][a_m]      = pa0[3];   \
    As[buf][a_k+0][a_m+64]   = pa1[0]; As[buf][a_k+1][a_m+64]   = pa1[1];   \
    As[buf][a_k+2][a_m+64]   = pa1[2]; As[buf][a_k+3][a_m+64]   = pa1[3];   \
    *(f4*)&Ws[buf][w_k][w_n] = pw0; }

    float acc[8][4] = {};

    G_LOAD(0);
    LDS_WRITE(0);
    __syncthreads();

    int cur = 0;
    for (int kt = 0; kt < NK; ++kt) {
        if (kt + 1 < NK) G_LOAD(kt + 1);
        #pragma unroll 4
        for (int k = 0; k < BK; ++k) {
            f4 af0 = *(const f4*)&As[cur][k][4 * ty];
            f4 af1 = *(const f4*)&As[cur][k][64 + 4 * ty];
            f4 bf  = *(const f4*)&Ws[cur][k][4 * tx];
            #pragma unroll
            for (int i = 0; i < 4; ++i) {
                #pragma unroll
                for (int j = 0; j < 4; ++j) {
                    acc[i][j]     = fmaf(af0[i], bf[j], acc[i][j]);
                    acc[i+4][j]   = fmaf(af1[i], bf[j], acc[i+4][j]);
                }
            }
        }
        if (kt + 1 < NK) LDS_WRITE(cur ^ 1);   // other buffer: no pre-barrier
        __syncthreads();
        cur ^= 1;
    }

    f4 biasv = *(const f4*)&bias[n0 + 4 * tx];
    #pragma unroll
    for (int i = 0; i < 8; ++i) {
        const int m = m0 + 4 * ty + ((i < 4) ? i : (64 + i - 4));
        f4 v;
        #pragma unroll
        for (int j = 0; j < 4; ++j) v[j] = acc[i][j] + biasv[j];
        if (OUT_MODE == 0) {
            *(f4*)(C + (size_t)m * N + n0 + 4 * tx) = v;
        } else {
            const int b = m >> 11, s = m & (SS - 1);
            const int na = n0 + 4 * tx;
            float* da = C + ((size_t)(b * NHH + (na >> 6)) * SS + s) * HDD + (na & 63);
            *(f4*)da = v;
        }
    }
#undef G_LOAD
#undef LDS_WRITE
}

// ----------------------------------------------------------------------
// Flash-style attention with k = v = q and floored integer scores.
// q: [B*NH][S][64]  ->  o: [B][S][HID]
// Block: 256 threads, 64 Q-rows per block, 64-wide K/V tiles.
// LDS: q_s (swz, pre-scaled by 1/8), k_s (swz, serves V),
//      k_t (transposed, serves QK), P_s.  64 KB -> 2 blocks/CU.
// 1D grid of 1024 blocks, XCD-chunked: XCD k owns heads 4k..4k+3
// (4 x 512KB K-panels = 2MB resident in its 4MB L2).
// Inner loops are VALU-bound: qf/pf reads are 16-way lane-broadcast and
// kf/vf reads 4-way broadcast, so LDS BW is ~4-16x under the naive
// accounting; ~4096 VALU-cy vs ~300 LDS-cy per wave per tile.
__global__ __launch_bounds__(256)
void attn_kernel(const float* __restrict__ q, float* __restrict__ o)
{
    constexpr int TS = 64;
    __shared__ float q_s[TS * 64];     // swizzled [r][d], values *0.125 (exact)
    __shared__ float k_s[TS * 64];     // swizzled [c][d]  (V reads)
    __shared__ float k_t[64][TS];      // [d][c]           (QK reads)
    __shared__ float P_s[TS][TS];      // [r][c]

    const int tid = threadIdx.x;
    const int tx = tid & 15, ty = tid >> 4;

    // XCD-aware bijective remap: 1024 blocks = 8 XCDs x 128
    const int swzb = (blockIdx.x & 7) * 128 + (blockIdx.x >> 3);
    const int qb = swzb & 31;          // 0..31 (S/64), fast within XCD chunk
    const int bh = swzb >> 5;          // 0..31 (B*NH), 4 heads per XCD

    // swizzled flat index: row r, 4-word chunk w (0..15)
    #define SWZ(r, w) (((r) << 6) + (((w) ^ ((r) & 15)) << 2))

    const float* qhead = q + (size_t)bh * SS * 64;

    const int st_r = tid >> 2;             // 0..63
    const int st_w = (tid & 3) * 4;        // word chunk base

    // ---- load Q tile (rows qb*64..), pre-scale by 1/8 (exact pow2) ----
    {
        const float* src = qhead + (size_t)(qb * TS + st_r) * 64 + st_w * 4;
        #pragma unroll
        for (int i = 0; i < 4; ++i) {
            f4 vq = *(const f4*)(src + 4 * i);
            #pragma unroll
            for (int j = 0; j < 4; ++j) vq[j] *= 0.125f;
            *(f4*)&q_s[SWZ(st_r, st_w + i)] = vq;
        }
    }

    float acc_o[4][4] = {};
    float m_r[4] = {-1e30f, -1e30f, -1e30f, -1e30f};
    float l_r[4] = {};

    // prefetch K tile 0 into regs
    f4 pk[4];
    {
        const float* src = qhead + (size_t)st_r * 64 + st_w * 4;
        #pragma unroll
        for (int i = 0; i < 4; ++i) pk[i] = *(const f4*)(src + 4 * i);
    }

    for (int kt = 0; kt < SS / TS; ++kt) {
        __syncthreads();   // prev PV done with k_s/P_s (and Q write visible)
        // ---- write staged K tile: k_s (swizzled) + k_t (transposed) ----
        #pragma unroll
        for (int i = 0; i < 4; ++i) {
            *(f4*)&k_s[SWZ(st_r, st_w + i)] = pk[i];
            const int d = (st_w + i) * 4;
            k_t[d + 0][st_r] = pk[i][0];
            k_t[d + 1][st_r] = pk[i][1];
            k_t[d + 2][st_r] = pk[i][2];
            k_t[d + 3][st_r] = pk[i][3];
        }
        __syncthreads();
        // prefetch next K tile (latency hidden under QK+softmax+PV)
        if (kt + 1 < SS / TS) {
            const float* src = qhead + (size_t)((kt + 1) * TS + st_r) * 64 + st_w * 4;
            #pragma unroll
            for (int i = 0; i < 4; ++i) pk[i] = *(const f4*)(src + 4 * i);
        }

        // ---- QK^T: sc[i][j] = (q/8)[4ty+i] . k[4tx+j] ----
        float sc[4][4] = {};
        #pragma unroll 2
        for (int w = 0; w < 16; ++w) {
            f4 qf[4], kf[4];
            #pragma unroll
            for (int i = 0; i < 4; ++i) qf[i] = *(const f4*)&q_s[SWZ(4 * ty + i, w)];
            #pragma unroll
            for (int l = 0; l < 4; ++l) kf[l] = *(const f4*)&k_t[4 * w + l][4 * tx];
            #pragma unroll
            for (int l = 0; l < 4; ++l)
                #pragma unroll
                for (int i = 0; i < 4; ++i)
                    #pragma unroll
                    for (int j = 0; j < 4; ++j)
                        sc[i][j] = fmaf(qf[i][l], kf[l][j], sc[i][j]);
        }

        // ---- floored scores + online softmax ----
        #pragma unroll
        for (int i = 0; i < 4; ++i) {
            #pragma unroll
            for (int j = 0; j < 4; ++j)
                sc[i][j] = floorf(sc[i][j]);
            float mx = fmaxf(fmaxf(sc[i][0], sc[i][1]), fmaxf(sc[i][2], sc[i][3]));
            #pragma unroll
            for (int w = 1; w < 16; w <<= 1)
                mx = fmaxf(mx, __shfl_xor(mx, w, 16));
            const float mn = fmaxf(m_r[i], mx);
            const float corr = __expf(m_r[i] - mn);
            m_r[i] = mn;
            f4 p;
            float sum = 0.f;
            #pragma unroll
            for (int j = 0; j < 4; ++j) { p[j] = __expf(sc[i][j] - mn); sum += p[j]; }
            #pragma unroll
            for (int w = 1; w < 16; w <<= 1)
                sum += __shfl_xor(sum, w, 16);
            l_r[i] = l_r[i] * corr + sum;
            #pragma unroll
            for (int j = 0; j < 4; ++j) acc_o[i][j] *= corr;
            *(f4*)&P_s[4 * ty + i][4 * tx] = p;
        }
        __syncthreads();

        // ---- PV: acc_o[i][j] += sum_c P[4ty+i][c] * V[c][4tx+j]  (V = K) ----
        #pragma unroll 2
        for (int c = 0; c < TS; c += 4) {
            f4 pf[4], vf[4];
            #pragma unroll
            for (int i = 0; i < 4; ++i) pf[i] = *(const f4*)&P_s[4 * ty + i][c];
            #pragma unroll
            for (int l = 0; l < 4; ++l) vf[l] = *(const f4*)&k_s[SWZ(c + l, tx)];
            #pragma unroll
            for (int l = 0; l < 4; ++l)
                #pragma unroll
                for (int i = 0; i < 4; ++i)
                    #pragma unroll
                    for (int j = 0; j < 4; ++j)
                        acc_o[i][j] = fmaf(pf[i][l], vf[l][j], acc_o[i][j]);
        }
    }

    // ---- epilogue: normalize, write o[b][s][h*64+d] ----
    const int b = bh >> 4, h = bh & 15;
    #pragma unroll
    for (int i = 0; i < 4; ++i) {
        const float inv = 1.0f / l_r[i];
        f4 v;
        #pragma unroll
        for (int j = 0; j < 4; ++j) v[j] = acc_o[i][j] * inv;
        const int srow = qb * TS + 4 * ty + i;
        *(f4*)(o + ((size_t)(b * SS + srow)) * HIDD + h * HDD + 4 * tx) = v;
    }
    #undef SWZ
}

// ----------------------------------------------------------------------
extern "C" void kernel_launch(void* const* d_in, const int* in_sizes, int n_in,
                              void* d_out, int out_size, void* d_ws, size_t ws_size,
                              hipStream_t stream)
{
    const float* x  = (const float*)d_in[0];
    const float* Wq = (const float*)d_in[1];
    const float* bq = (const float*)d_in[2];
    const float* Wo = (const float*)d_in[3];
    const float* bo = (const float*)d_in[4];
    float* out = (float*)d_out;

    float* q_ws    = (float*)d_ws;                       // [B*NH][S][64] = 16 MB
    float* attn_ws = q_ws + (size_t)BB * SS * HIDD;      // [B][S][HID]   = 16 MB

    // 1) q = x @ Wq + bq  -> [B,H,S,D] layout
    gemm_kernel<1><<<512, 256, 0, stream>>>(x, Wq, bq, q_ws);
    // 2) attention (k = v = q), floored scores
    attn_kernel<<<1024, 256, 0, stream>>>(q_ws, attn_ws);
    // 3) out = attn @ Wo + bo
    gemm_kernel<0><<<512, 256, 0, stream>>>(attn_ws, Wo, bo, out);
}